// Round 3
// baseline (420.429 us; speedup 1.0000x reference)
//
#include <hip/hip_runtime.h>
#include <hip/hip_bf16.h>

// N=4, T=8 -> NT=32 batches; C=C2=256; H*W=1024.
// Single fused kernel. Block = (nt, 64-q strip), 512 threads (8 waves).
// Pass 1: scores GEMM (Q resident in LDS, K tiled 256p x 64c chunks),
//         e = exp(s/16) stored f32 DIRECTLY at its final attn location;
//         colsum accumulated in registers (block owns all p for its cols).
// Pass 2: read e back (own strip only -> same-CU L1/L2 hot), attn = e*inv
//         written in place (f32, full precision), PV GEMM
//         pval[c,q] = sum_p V[c,p]*attn[p,q]  via 32x32x16 bf16 MFMA.
// Race-freedom: each block exclusively owns its 64-column strip of attn;
// within a block, pass-1 writes are ordered before pass-2 reads by
// __syncthreads (vmcnt-drained); pass-2 prefetch of tile t+1 reads rows
// [64t+64, 64t+127] which no attn write (rows <= 64t+63) has touched.
// Numerics identical to the accepted round-0 path (f32 e, f32 colsum,
// bf16 attn only inside the PV MFMA).
// d_out = [ p_val : 32*256*1024 f32 ][ attn : 32*1024*1024 f32 ]

#define NT_BATCH 32
#define CDIM     256
#define HW       1024

using short8 = __attribute__((ext_vector_type(8))) short;   // 8 bf16 (4 VGPRs)
using f32x16 = __attribute__((ext_vector_type(16))) float;  // 32x32 MFMA acc
using f32x4v = __attribute__((ext_vector_type(4))) float;

__device__ __forceinline__ unsigned pk2(float a, float b) {
  float2 t; t.x = a; t.y = b;
  __hip_bfloat162 h = __float22bfloat162_rn(t);   // v_cvt_pk_bf16_f32
  return *reinterpret_cast<unsigned*>(&h);
}
__device__ __forceinline__ void wr64(void* dst, float a, float b, float c, float d) {
  uint2 v; v.x = pk2(a, b); v.y = pk2(c, d);
  *reinterpret_cast<uint2*>(dst) = v;
}

// LDS union: pass-1 (Qs+As) overlaid with pass-2 (Vs+Ps). 70656 B ->
// 2 blocks/CU = 16 waves/CU (~50% occupancy).
union SMEM {
  struct { unsigned short Qs[64][264]; unsigned short As[256][72]; } a;  // 33792+36864
  struct { unsigned short Vs[256][72]; unsigned short Ps[64][72]; } b;   // 36864+9216
};

__global__ __launch_bounds__(512, 4) void k_fused(const float* __restrict__ Kp,
                                                  const float* __restrict__ Qp,
                                                  const float* __restrict__ Vp,
                                                  float* __restrict__ A_out,
                                                  float* __restrict__ O) {
  __shared__ __align__(16) SMEM sm;
  __shared__ float csum[64];
  __shared__ float inv_s[64];

  // XCD-chunked swizzle: consecutive hw blocks round-robin XCDs; give each
  // XCD 64 logical blocks (=4 nt) so a batch's K/V panels stay in one L2.
  const int hbid = blockIdx.y * 16 + blockIdx.x;            // 0..511
  const int lbid = ((hbid & 7) << 6) | (hbid >> 3);         // bijective
  const int nt = lbid >> 4;
  const int q0 = (lbid & 15) << 6;

  const float* Kb = Kp + (size_t)nt * (CDIM * HW);
  const float* Qb = Qp + (size_t)nt * (CDIM * HW);
  const float* Vb = Vp + (size_t)nt * (CDIM * HW);
  float* Ab = A_out + (size_t)nt * (HW * HW);
  float* Ob = O + (size_t)nt * (CDIM * HW);

  const int t = threadIdx.x, lane = t & 63;
  const int wave = t >> 6;            // 0..7
  const int l31 = lane & 31, lhi = lane >> 5;

  if (t < 64) csum[t] = 0.f;

  // ---- stage Q resident: Qs[q][c], 64q x 256c (2 tasks/thread) ----
  #pragma unroll
  for (int j2 = 0; j2 < 2; ++j2) {
    const int u = t + (j2 << 9);
    const int cb4 = (u & 63) << 2, qb4 = (u >> 6) << 2;
    f32x4v qv[4];
    #pragma unroll
    for (int j = 0; j < 4; ++j)
      qv[j] = *(const f32x4v*)&Qb[(size_t)(cb4 + j) * HW + q0 + qb4];
    #pragma unroll
    for (int i = 0; i < 4; ++i)
      wr64(&sm.a.Qs[qb4 + i][cb4], qv[0][i], qv[1][i], qv[2][i], qv[3][i]);
  }

  // ---- pass 1: scores + e (f32, to final attn slot) + colsum ----
  f32x4v kreg[2][4];
  auto loadK = [&](int P0_, int C0_) {
    #pragma unroll
    for (int j2 = 0; j2 < 2; ++j2) {
      const int u = t + (j2 << 9);
      const int cb = (u & 15) << 2, pp = (u >> 4) << 2;
      #pragma unroll
      for (int j = 0; j < 4; ++j)
        kreg[j2][j] = *(const f32x4v*)&Kb[(size_t)(C0_ + cb + j) * HW + P0_ + pp];
    }
  };

  float part[2] = {0.f, 0.f};
  loadK(0, 0);
  for (int pt = 0; pt < 4; ++pt) {
    const int P0 = pt << 8;
    f32x16 acc[2];
    #pragma unroll
    for (int n = 0; n < 2; ++n)
      #pragma unroll
      for (int r = 0; r < 16; ++r) acc[n][r] = 0.f;

    #pragma unroll
    for (int cc = 0; cc < 4; ++cc) {
      __syncthreads();   // A: previous chunk's fragment reads complete
      #pragma unroll
      for (int j2 = 0; j2 < 2; ++j2) {
        const int u = t + (j2 << 9);
        const int cb = (u & 15) << 2, pp = (u >> 4) << 2;
        #pragma unroll
        for (int i = 0; i < 4; ++i)
          wr64(&sm.a.As[pp + i][cb],
               kreg[j2][0][i], kreg[j2][1][i], kreg[j2][2][i], kreg[j2][3][i]);
      }
      // prefetch next chunk: latency hidden under barrier B + MFMAs
      if (cc < 3) loadK(P0, (cc + 1) << 6);
      else if (pt < 3) loadK(P0 + 256, 0);
      __syncthreads();   // B: As visible
      #pragma unroll
      for (int ks = 0; ks < 4; ++ks) {
        short8 a_ = *(const short8*)&sm.a.As[wave * 32 + l31][ks * 16 + lhi * 8];
        short8 b0 = *(const short8*)&sm.a.Qs[l31][(cc << 6) + ks * 16 + lhi * 8];
        short8 b1 = *(const short8*)&sm.a.Qs[32 + l31][(cc << 6) + ks * 16 + lhi * 8];
        acc[0] = __builtin_amdgcn_mfma_f32_32x32x16_bf16(a_, b0, acc[0], 0, 0, 0);
        acc[1] = __builtin_amdgcn_mfma_f32_32x32x16_bf16(a_, b1, acc[1], 0, 0, 0);
      }
    }

    // epilogue: e = exp(s/16) -> f32 store at final attn location; colsum
    const int rbase = wave * 32 + (lhi << 2);
    #pragma unroll
    for (int n = 0; n < 2; ++n) {
      const int col = q0 + n * 32 + l31;
      #pragma unroll
      for (int r = 0; r < 16; ++r) {
        float e = __expf(acc[n][r] * 0.0625f);
        part[n] += e;
        const int row = P0 + rbase + (r & 3) + ((r >> 2) << 3);
        Ab[(size_t)row * HW + col] = e;
      }
    }
  }

  // ---- colsum reduce -> inv (block sees all p for its columns) ----
  atomicAdd(&csum[l31], part[0]);
  atomicAdd(&csum[32 + l31], part[1]);
  __syncthreads();
  if (t < 64) inv_s[t] = 1.0f / csum[t];
  __syncthreads();

  // ---- pass 2: in-place normalize + attn write + PV GEMM ----
  const int pr2 = t >> 4;              // pair-row: rows 2pr2, 2pr2+1 of tile
  const int sq = (t & 15) << 2;        // 4 q columns
  const f32x4v inv4 = *(const f32x4v*)&inv_s[sq];
  const int vc = t >> 1, vp = (t & 1) << 5;   // V staging: 2 threads / c-row

  f32x4v er[2];
  f32x4v vreg[8];
  auto loadE = [&](int pb_) {
    er[0] = *(const f32x4v*)&Ab[(size_t)(pb_ + 2 * pr2) * HW + q0 + sq];
    er[1] = *(const f32x4v*)&Ab[(size_t)(pb_ + 2 * pr2 + 1) * HW + q0 + sq];
  };
  auto loadV = [&](int pb_) {
    #pragma unroll
    for (int g = 0; g < 8; ++g)
      vreg[g] = *(const f32x4v*)&Vb[(size_t)vc * HW + pb_ + vp + (g << 2)];
  };

  f32x16 av[2];
  #pragma unroll
  for (int n = 0; n < 2; ++n)
    #pragma unroll
    for (int r = 0; r < 16; ++r) av[n][r] = 0.f;

  loadE(0); loadV(0);
  for (int tile = 0; tile < 16; ++tile) {
    const int pb = tile << 6;
    const f32x4v a0 = er[0] * inv4;
    const f32x4v a1 = er[1] * inv4;
    __syncthreads();   // A: previous tile's fragment reads complete
    #pragma unroll
    for (int j = 0; j < 4; ++j)
      *reinterpret_cast<unsigned*>(&sm.b.Ps[sq + j][2 * pr2]) = pk2(a0[j], a1[j]);
    #pragma unroll
    for (int g = 0; g < 4; ++g) {
      uint4 w_;
      w_.x = pk2(vreg[2 * g][0], vreg[2 * g][1]);
      w_.y = pk2(vreg[2 * g][2], vreg[2 * g][3]);
      w_.z = pk2(vreg[2 * g + 1][0], vreg[2 * g + 1][1]);
      w_.w = pk2(vreg[2 * g + 1][2], vreg[2 * g + 1][3]);
      *reinterpret_cast<uint4*>(&sm.b.Vs[vc][vp + (g << 3)]) = w_;
    }
    // prefetch next tile: its e rows [pb+64, pb+127] are untouched by any
    // attn write so far (those cover rows < pb+64) -> race-free
    if (tile < 15) { loadE(pb + 64); loadV(pb + 64); }
    // attn output (f32, in-place over own strip; this thread read these
    // exact cells into er before this phase)
    *(f32x4v*)&Ab[(size_t)(pb + 2 * pr2) * HW + q0 + sq] = a0;
    *(f32x4v*)&Ab[(size_t)(pb + 2 * pr2 + 1) * HW + q0 + sq] = a1;
    __syncthreads();   // B: Ps/Vs visible
    #pragma unroll
    for (int kk = 0; kk < 4; ++kk) {
      short8 a_ = *(const short8*)&sm.b.Vs[wave * 32 + l31][kk * 16 + lhi * 8];
      short8 b0 = *(const short8*)&sm.b.Ps[l31][kk * 16 + lhi * 8];
      short8 b1 = *(const short8*)&sm.b.Ps[32 + l31][kk * 16 + lhi * 8];
      av[0] = __builtin_amdgcn_mfma_f32_32x32x16_bf16(a_, b0, av[0], 0, 0, 0);
      av[1] = __builtin_amdgcn_mfma_f32_32x32x16_bf16(a_, b1, av[1], 0, 0, 0);
    }
  }

  // ---- pval epilogue ----
  #pragma unroll
  for (int n = 0; n < 2; ++n) {
    const int col = q0 + n * 32 + l31;
    const int cbase = wave * 32 + (lhi << 2);
    #pragma unroll
    for (int r = 0; r < 16; ++r) {
      const int c = cbase + (r & 3) + ((r >> 2) << 3);
      Ob[(size_t)c * HW + col] = av[n][r];
    }
  }
}

// ---------------------------------------------------------------------------
extern "C" void kernel_launch(void* const* d_in, const int* in_sizes, int n_in,
                              void* d_out, int out_size, void* d_ws, size_t ws_size,
                              hipStream_t stream) {
  const float* key   = (const float*)d_in[0];
  const float* query = (const float*)d_in[1];
  const float* value = (const float*)d_in[2];
  float* out  = (float*)d_out;
  float* pval = out;
  float* attn = out + (size_t)NT_BATCH * CDIM * HW;

  k_fused<<<dim3(16, NT_BATCH), 512, 0, stream>>>(key, query, value, attn, pval);
}

// Round 4
// 406.912 us; speedup vs baseline: 1.0332x; 1.0332x over previous
//
#include <hip/hip_runtime.h>
#include <hip/hip_bf16.h>

// N=4, T=8 -> NT=32 batches; C=C2=256; H*W=1024.
// Single fused kernel. Block = (nt, 64-q strip), 512 threads (8 waves).
// Pass 1: scores GEMM (Q resident in LDS, K tiled 256p x 64c chunks),
//         e = exp(s/16) stored f32 DIRECTLY at its final attn location;
//         colsum accumulated in registers.
// Pass 2: read e back, attn = e*inv written in place (f32), PV GEMM
//         pval[c,q] = sum_p V[c,p]*attn[p,q]  via 32x32x16 bf16 MFMA.
//
// ROUND-4 CHANGE (sync structure only): per-phase __syncthreads() replaced
// by raw s_barrier + s_waitcnt lgkmcnt(0) (sched_barrier-fenced). LDS
// correctness needs only lgkm drain; global prefetch loads now stay in
// flight across barriers (previously __syncthreads' vmcnt(0) drained the
// prefetch just issued -> full latency exposed every phase). Pass
// boundaries keep full __syncthreads() (vmcnt drain needed for e-store
// visibility). Pass-2 e-prefetch deepened to 2 tiles; setprio around MFMA.
//
// Race-freedom: block exclusively owns its 64-col attn strip; pass-1 writes
// ordered before pass-2 reads by the full __syncthreads at the colsum
// boundary; pass-2 prefetch of tile t+2 reads rows >= 64t+128 while all
// attn writes so far cover rows <= 64t+63.
// d_out = [ p_val : 32*256*1024 f32 ][ attn : 32*1024*1024 f32 ]

#define NT_BATCH 32
#define CDIM     256
#define HW       1024

using short8 = __attribute__((ext_vector_type(8))) short;   // 8 bf16 (4 VGPRs)
using f32x16 = __attribute__((ext_vector_type(16))) float;  // 32x32 MFMA acc
using f32x4v = __attribute__((ext_vector_type(4))) float;

__device__ __forceinline__ unsigned pk2(float a, float b) {
  float2 t; t.x = a; t.y = b;
  __hip_bfloat162 h = __float22bfloat162_rn(t);   // v_cvt_pk_bf16_f32
  return *reinterpret_cast<unsigned*>(&h);
}
__device__ __forceinline__ void wr64(void* dst, float a, float b, float c, float d) {
  uint2 v; v.x = pk2(a, b); v.y = pk2(c, d);
  *reinterpret_cast<uint2*>(dst) = v;
}

// Raw barrier: drains this wave's LDS ops only; VMEM stays in flight.
// sched_barrier(0) on both sides pins all surrounding code (rule #18).
__device__ __forceinline__ void barrier_lgkm() {
  __builtin_amdgcn_sched_barrier(0);
  asm volatile("s_waitcnt lgkmcnt(0)" ::: "memory");
  __builtin_amdgcn_s_barrier();
  __builtin_amdgcn_sched_barrier(0);
}

// LDS union: pass-1 (Qs+As) overlaid with pass-2 (Vs+Ps). 70656 B ->
// 2 blocks/CU = 16 waves/CU.
union SMEM {
  struct { unsigned short Qs[64][264]; unsigned short As[256][72]; } a;  // 33792+36864
  struct { unsigned short Vs[256][72]; unsigned short Ps[64][72]; } b;   // 36864+9216
};

__global__ __launch_bounds__(512, 4) void k_fused(const float* __restrict__ Kp,
                                                  const float* __restrict__ Qp,
                                                  const float* __restrict__ Vp,
                                                  float* __restrict__ A_out,
                                                  float* __restrict__ O) {
  __shared__ __align__(16) SMEM sm;
  __shared__ float csum[64];
  __shared__ float inv_s[64];

  // XCD-chunked swizzle: consecutive hw blocks round-robin XCDs; each XCD
  // gets 64 logical blocks (=4 nt) so a batch's K/V panels stay in one L2.
  const int hbid = blockIdx.y * 16 + blockIdx.x;            // 0..511
  const int lbid = ((hbid & 7) << 6) | (hbid >> 3);         // bijective
  const int nt = lbid >> 4;
  const int q0 = (lbid & 15) << 6;

  const float* Kb = Kp + (size_t)nt * (CDIM * HW);
  const float* Qb = Qp + (size_t)nt * (CDIM * HW);
  const float* Vb = Vp + (size_t)nt * (CDIM * HW);
  float* Ab = A_out + (size_t)nt * (HW * HW);
  float* Ob = O + (size_t)nt * (CDIM * HW);

  const int t = threadIdx.x, lane = t & 63;
  const int wave = t >> 6;            // 0..7
  const int l31 = lane & 31, lhi = lane >> 5;

  if (t < 64) csum[t] = 0.f;

  // ---- stage Q resident: Qs[q][c], 64q x 256c (2 tasks/thread) ----
  #pragma unroll
  for (int j2 = 0; j2 < 2; ++j2) {
    const int u = t + (j2 << 9);
    const int cb4 = (u & 63) << 2, qb4 = (u >> 6) << 2;
    f32x4v qv[4];
    #pragma unroll
    for (int j = 0; j < 4; ++j)
      qv[j] = *(const f32x4v*)&Qb[(size_t)(cb4 + j) * HW + q0 + qb4];
    #pragma unroll
    for (int i = 0; i < 4; ++i)
      wr64(&sm.a.Qs[qb4 + i][cb4], qv[0][i], qv[1][i], qv[2][i], qv[3][i]);
  }

  // ---- pass 1: scores + e (f32, to final attn slot) + colsum ----
  f32x4v kreg[2][4];
  auto loadK = [&](int P0_, int C0_) {
    #pragma unroll
    for (int j2 = 0; j2 < 2; ++j2) {
      const int u = t + (j2 << 9);
      const int cb = (u & 15) << 2, pp = (u >> 4) << 2;
      #pragma unroll
      for (int j = 0; j < 4; ++j)
        kreg[j2][j] = *(const f32x4v*)&Kb[(size_t)(C0_ + cb + j) * HW + P0_ + pp];
    }
  };

  float part[2] = {0.f, 0.f};
  loadK(0, 0);
  #pragma unroll
  for (int pt = 0; pt < 4; ++pt) {
    const int P0 = pt << 8;
    f32x16 acc[2];
    #pragma unroll
    for (int n = 0; n < 2; ++n)
      #pragma unroll
      for (int r = 0; r < 16; ++r) acc[n][r] = 0.f;

    #pragma unroll
    for (int cc = 0; cc < 4; ++cc) {
      barrier_lgkm();   // A: all waves' fragment ds_reads complete
      #pragma unroll
      for (int j2 = 0; j2 < 2; ++j2) {
        const int u = t + (j2 << 9);
        const int cb = (u & 15) << 2, pp = (u >> 4) << 2;
        #pragma unroll
        for (int i = 0; i < 4; ++i)
          wr64(&sm.a.As[pp + i][cb],
               kreg[j2][0][i], kreg[j2][1][i], kreg[j2][2][i], kreg[j2][3][i]);
      }
      // prefetch next chunk: stays IN FLIGHT across barrier B (lgkm-only)
      if (cc < 3) loadK(P0, (cc + 1) << 6);
      else if (pt < 3) loadK(P0 + 256, 0);
      barrier_lgkm();   // B: staging ds_writes drained + visible
      __builtin_amdgcn_s_setprio(1);
      #pragma unroll
      for (int ks = 0; ks < 4; ++ks) {
        short8 a_ = *(const short8*)&sm.a.As[wave * 32 + l31][ks * 16 + lhi * 8];
        short8 b0 = *(const short8*)&sm.a.Qs[l31][(cc << 6) + ks * 16 + lhi * 8];
        short8 b1 = *(const short8*)&sm.a.Qs[32 + l31][(cc << 6) + ks * 16 + lhi * 8];
        acc[0] = __builtin_amdgcn_mfma_f32_32x32x16_bf16(a_, b0, acc[0], 0, 0, 0);
        acc[1] = __builtin_amdgcn_mfma_f32_32x32x16_bf16(a_, b1, acc[1], 0, 0, 0);
      }
      __builtin_amdgcn_s_setprio(0);
    }

    // epilogue: e = exp(s/16) -> f32 store at final attn location; colsum.
    // Stores stay in flight until the pass-boundary __syncthreads.
    const int rbase = wave * 32 + (lhi << 2);
    #pragma unroll
    for (int n = 0; n < 2; ++n) {
      const int col = q0 + n * 32 + l31;
      #pragma unroll
      for (int r = 0; r < 16; ++r) {
        float e = __expf(acc[n][r] * 0.0625f);
        part[n] += e;
        const int row = P0 + rbase + (r & 3) + ((r >> 2) << 3);
        Ab[(size_t)row * HW + col] = e;
      }
    }
  }

  // ---- colsum reduce -> inv; FULL syncthreads (drains e stores: vmcnt) ----
  atomicAdd(&csum[l31], part[0]);
  atomicAdd(&csum[32 + l31], part[1]);
  __syncthreads();
  if (t < 64) inv_s[t] = 1.0f / csum[t];
  __syncthreads();

  // ---- pass 2: in-place normalize + attn write + PV GEMM ----
  const int pr2 = t >> 4;              // pair-row: rows 2pr2, 2pr2+1 of tile
  const int sq = (t & 15) << 2;        // 4 q columns
  const f32x4v inv4 = *(const f32x4v*)&inv_s[sq];
  const int vc = t >> 1, vp = (t & 1) << 5;   // V staging: 2 threads / c-row

  f32x4v er[2][2];                     // 2-deep e prefetch (per-block stream,
  f32x4v vreg[8];                      //   L2-missing); V 1-deep (L2-hot)
  auto loadE = [&](int buf, int pb_) {
    er[buf][0] = *(const f32x4v*)&Ab[(size_t)(pb_ + 2 * pr2) * HW + q0 + sq];
    er[buf][1] = *(const f32x4v*)&Ab[(size_t)(pb_ + 2 * pr2 + 1) * HW + q0 + sq];
  };
  auto loadV = [&](int pb_) {
    #pragma unroll
    for (int g = 0; g < 8; ++g)
      vreg[g] = *(const f32x4v*)&Vb[(size_t)vc * HW + pb_ + vp + (g << 2)];
  };

  f32x16 av[2];
  #pragma unroll
  for (int n = 0; n < 2; ++n)
    #pragma unroll
    for (int r = 0; r < 16; ++r) av[n][r] = 0.f;

  loadE(0, 0); loadV(0); loadE(1, 64);
  #pragma unroll
  for (int tile = 0; tile < 16; ++tile) {
    const int pb = tile << 6;
    const int cur = tile & 1;          // compile-time after full unroll
    const f32x4v a0 = er[cur][0] * inv4;
    const f32x4v a1 = er[cur][1] * inv4;
    barrier_lgkm();   // A: previous tile's fragment ds_reads complete
    #pragma unroll
    for (int j = 0; j < 4; ++j)
      *reinterpret_cast<unsigned*>(&sm.b.Ps[sq + j][2 * pr2]) = pk2(a0[j], a1[j]);
    #pragma unroll
    for (int g = 0; g < 4; ++g) {
      uint4 w_;
      w_.x = pk2(vreg[2 * g][0], vreg[2 * g][1]);
      w_.y = pk2(vreg[2 * g][2], vreg[2 * g][3]);
      w_.z = pk2(vreg[2 * g + 1][0], vreg[2 * g + 1][1]);
      w_.w = pk2(vreg[2 * g + 1][2], vreg[2 * g + 1][3]);
      *reinterpret_cast<uint4*>(&sm.b.Vs[vc][vp + (g << 3)]) = w_;
    }
    // prefetch (in flight across barrier B): V for t+1, e for t+2.
    // e rows of t+2 (>= pb+128) untouched by any attn write (<= pb+63).
    if (tile < 15) loadV(pb + 64);
    if (tile < 14) loadE(cur, pb + 128);
    // attn output (f32, in-place over own strip; this thread already holds
    // these exact cells in registers) — store stays in flight.
    *(f32x4v*)&Ab[(size_t)(pb + 2 * pr2) * HW + q0 + sq] = a0;
    *(f32x4v*)&Ab[(size_t)(pb + 2 * pr2 + 1) * HW + q0 + sq] = a1;
    barrier_lgkm();   // B: Ps/Vs staged + visible
    __builtin_amdgcn_s_setprio(1);
    #pragma unroll
    for (int kk = 0; kk < 4; ++kk) {
      short8 a_ = *(const short8*)&sm.b.Vs[wave * 32 + l31][kk * 16 + lhi * 8];
      short8 b0 = *(const short8*)&sm.b.Ps[l31][kk * 16 + lhi * 8];
      short8 b1 = *(const short8*)&sm.b.Ps[32 + l31][kk * 16 + lhi * 8];
      av[0] = __builtin_amdgcn_mfma_f32_32x32x16_bf16(a_, b0, av[0], 0, 0, 0);
      av[1] = __builtin_amdgcn_mfma_f32_32x32x16_bf16(a_, b1, av[1], 0, 0, 0);
    }
    __builtin_amdgcn_s_setprio(0);
  }

  // ---- pval epilogue ----
  #pragma unroll
  for (int n = 0; n < 2; ++n) {
    const int col = q0 + n * 32 + l31;
    const int cbase = wave * 32 + (lhi << 2);
    #pragma unroll
    for (int r = 0; r < 16; ++r) {
      const int c = cbase + (r & 3) + ((r >> 2) << 3);
      Ob[(size_t)c * HW + col] = av[n][r];
    }
  }
}

// ---------------------------------------------------------------------------
extern "C" void kernel_launch(void* const* d_in, const int* in_sizes, int n_in,
                              void* d_out, int out_size, void* d_ws, size_t ws_size,
                              hipStream_t stream) {
  const float* key   = (const float*)d_in[0];
  const float* query = (const float*)d_in[1];
  const float* value = (const float*)d_in[2];
  float* out  = (float*)d_out;
  float* pval = out;
  float* attn = out + (size_t)NT_BATCH * CDIM * HW;

  k_fused<<<dim3(16, NT_BATCH), 512, 0, stream>>>(key, query, value, attn, pval);
}